// Round 8
// baseline (543.441 us; speedup 1.0000x reference)
//
#include <hip/hip_runtime.h>
#include <cstdint>
#include <cstddef>

#define N_NODES 2048
#define N_EDGES 32768
#define ROW_CAP 384   // max row degree ~222 (mean 164, sd 12.8)
#define COL_CAP 48    // max col degree ~26  (mean 10.2, sd 3.2)

typedef unsigned short u16;
typedef __bf16 bf16x8 __attribute__((ext_vector_type(8)));
typedef float f32x4 __attribute__((ext_vector_type(4)));
typedef uint32_t u32x4 __attribute__((ext_vector_type(4)));

union BF8 {
  bf16x8 v;
  u16 s[8];
  uint4 q;
};

__device__ __forceinline__ u16 f2bf(float f) {
  uint32_t u = __float_as_uint(f);
  uint32_t r = (u + 0x7fffu + ((u >> 16) & 1u)) >> 16;  // RNE
  return (u16)r;
}
__device__ __forceinline__ float bf2f(u16 h) {
  return __uint_as_float(((uint32_t)h) << 16);
}
__device__ __forceinline__ float logsig(float x) {
  return fminf(x, 0.0f) - __logf(1.0f + __expf(-fabsf(x)));
}

// Load 8 consecutive f32 and pack to a bf16x8 MFMA fragment (activations).
__device__ __forceinline__ BF8 load_f32x8_bf(const float* __restrict__ p) {
  const float4 g0 = ((const float4*)p)[0];
  const float4 g1 = ((const float4*)p)[1];
  BF8 b;
  b.s[0] = f2bf(g0.x); b.s[1] = f2bf(g0.y);
  b.s[2] = f2bf(g0.z); b.s[3] = f2bf(g0.w);
  b.s[4] = f2bf(g1.x); b.s[5] = f2bf(g1.y);
  b.s[6] = f2bf(g1.z); b.s[7] = f2bf(g1.w);
  return b;
}

// ---------------------------------------------------------------------------
// K0: weights fp32->bf16 + zero col_cnt. (NEVER inline-convert weights in the
// MFMA hot loop: per-fragment f2bf is ~4 VALU x 8 elem x 32 frags per wave,
// dwarfing the ~640 cyc of MFMA issue -- measured R5->R7 = -57 us.)
// wb layout (elements): [0,16384)=W1m, [16384,32768)=W2m,
//                       [32768,53248)=W1a(128x160), [53248,69632)=W2a
// ---------------------------------------------------------------------------
__global__ __launch_bounds__(256) void conv_weights(
    const float* __restrict__ W1m, const float* __restrict__ W2m,
    const float* __restrict__ W1a, const float* __restrict__ W2a,
    u16* __restrict__ wb, int* __restrict__ col_cnt)
{
  const int i = blockIdx.x * 256 + threadIdx.x;
  if (i < N_EDGES) col_cnt[i] = 0;
  if (i < 16384)      wb[i] = f2bf(W1m[i]);
  else if (i < 32768) wb[i] = f2bf(W2m[i - 16384]);
  else if (i < 53248) wb[i] = f2bf(W1a[i - 32768]);
  else if (i < 69632) wb[i] = f2bf(W2a[i - 53248]);
}

// ---------------------------------------------------------------------------
// K1: MLP_m  s = ls(ls(state@W1m^T+b1m)@W2m^T) -> bf16.
// 512 blocks x 64 rows: 2 blocks/CU -> 2 waves/SIMD so weight-fragment loads
// hide under the co-resident wave's MFMAs (R7: part of the -57 us win).
// ---------------------------------------------------------------------------
__global__ __launch_bounds__(256) void mlp_m(
    const float* __restrict__ state, const u16* __restrict__ W1b,
    const float* __restrict__ b1, const u16* __restrict__ W2b,
    u16* __restrict__ s_out)
{
  const int tid = threadIdx.x;
  const int wave = tid >> 6;
  const int lane = tid & 63;
  const int l16 = lane & 15;
  const int quad = lane >> 4;
  const int row0 = blockIdx.x * 64;

  __shared__ u16 h_lds[64][136];

  const f32x4 vzero = {0.f, 0.f, 0.f, 0.f};
  f32x4 acc[8];
  for (int ct = 0; ct < 8; ++ct) acc[ct] = vzero;

  for (int kc = 0; kc < 4; ++kc) {
    const int k0 = kc * 32 + quad * 8;
    const BF8 a = load_f32x8_bf(state + (size_t)(row0 + wave * 16 + l16) * 128 + k0);
    for (int ct = 0; ct < 8; ++ct) {
      BF8 b;
      b.q = *(const uint4*)(W1b + (size_t)(ct * 16 + l16) * 128 + k0);
      acc[ct] = __builtin_amdgcn_mfma_f32_16x16x32_bf16(a.v, b.v, acc[ct], 0, 0, 0);
    }
  }

  for (int ct = 0; ct < 8; ++ct) {
    const int col = ct * 16 + l16;
    const float bias = b1[col];
    const int r = wave * 16 + quad * 4;
    for (int i = 0; i < 4; ++i)
      h_lds[r + i][col] = f2bf(logsig(acc[ct][i] + bias));
  }
  __syncthreads();

  f32x4 acc2[8];
  for (int ct = 0; ct < 8; ++ct) acc2[ct] = vzero;

  for (int kc = 0; kc < 4; ++kc) {
    const int k0 = kc * 32 + quad * 8;
    BF8 a;
    a.q = *(const uint4*)&h_lds[wave * 16 + l16][k0];
    for (int ct = 0; ct < 8; ++ct) {
      BF8 b;
      b.q = *(const uint4*)(W2b + (size_t)(ct * 16 + l16) * 128 + k0);
      acc2[ct] = __builtin_amdgcn_mfma_f32_16x16x32_bf16(a.v, b.v, acc2[ct], 0, 0, 0);
    }
  }

  for (int ct = 0; ct < 8; ++ct) {
    const int col = ct * 16 + l16;
    const int r = row0 + wave * 16 + quad * 4;
    for (int i = 0; i < 4; ++i)
      s_out[(size_t)(r + i) * 128 + col] = f2bf(logsig(acc2[ct][i]));
  }
}

// ---------------------------------------------------------------------------
// K2: fused scan + row-gather. COMPACTION SIMPLIFIED this round: the edge
// list is order-free (feeds an order-independent sum + an order-arbitrary
// col scatter), so the per-k ballot + lane0-atomic + prefix-popcount chain
// is replaced by direct per-lane LDS atomicAdd per nonzero word (~164
// atomics/block total). Wave-level `any` early-out (27% skip) and 2-deep
// load prefetch retained. One-sided: wins if compaction was the limiter,
// neutral if the 268 MB mask stream (43 us floor) is.
// ---------------------------------------------------------------------------
__global__ __launch_bounds__(256) void scan_gather(
    const float* __restrict__ mask, const u16* __restrict__ s_bf,
    int* __restrict__ col_cnt, int* __restrict__ col_nodes,
    float* __restrict__ y)
{
  const int n = blockIdx.x;
  const int tid = threadIdx.x;
  const int lane = tid & 63;

  __shared__ int cnt;
  __shared__ int list[ROW_CAP];
  __shared__ float part[3][128];

  if (tid == 0) cnt = 0;
  __syncthreads();

  const u32x4* row = (const u32x4*)(mask + (size_t)n * N_EDGES);
  u32x4 v0 = __builtin_nontemporal_load(&row[tid]);
  u32x4 v1 = __builtin_nontemporal_load(&row[tid + 256]);
#pragma unroll 1
  for (int t = 0; t < 16; ++t) {
    const int i = tid + t * 512;
    u32x4 n0 = {0u, 0u, 0u, 0u}, n1 = {0u, 0u, 0u, 0u};
    if (t < 15) {  // wave-uniform
      n0 = __builtin_nontemporal_load(&row[i + 512]);
      n1 = __builtin_nontemporal_load(&row[i + 768]);
    }
#pragma unroll
    for (int h = 0; h < 2; ++h) {
      const u32x4 v = h ? v1 : v0;
      const int ib = i + h * 256;
      const uint32_t any = v[0] | v[1] | v[2] | v[3];
      if (__ballot(any != 0u)) {
#pragma unroll
        for (int k = 0; k < 4; ++k) {
          if (v[k] != 0u) {
            const int slot = atomicAdd(&cnt, 1);
            if (slot < ROW_CAP) list[slot] = ib * 4 + k;
          }
        }
      }
    }
    v0 = n0; v1 = n1;
  }
  __syncthreads();

  const int c = min(cnt, ROW_CAP);

  // col scatter (feeds pass_b)
  for (int i = tid; i < c; i += 256) {
    const int e = list[i];
    const int slot = atomicAdd(&col_cnt[e], 1);
    if (slot < COL_CAP) col_nodes[(size_t)e * COL_CAP + slot] = n;
  }

  // row gather: 4 waves, each covers all 128 dims (2 dims/lane, u32 loads)
  const int wv = tid >> 6;
  const int d0 = lane * 2;
  float a0 = 0.f, a1 = 0.f;
#pragma unroll 4
  for (int i = wv; i < c; i += 4) {
    const uint32_t sp = *(const uint32_t*)&s_bf[(size_t)list[i] * 128 + d0];
    a0 += bf2f((u16)(sp & 0xffffu));
    a1 += bf2f((u16)(sp >> 16));
  }
  if (wv > 0) { part[wv - 1][d0] = a0; part[wv - 1][d0 + 1] = a1; }
  __syncthreads();
  if (wv == 0) {
    a0 += part[0][d0] + part[1][d0] + part[2][d0];
    a1 += part[0][d0 + 1] + part[1][d0 + 1] + part[2][d0 + 1];
    float2 r; r.x = a0; r.y = a1;
    *(float2*)&y[n * 128 + d0] = r;
  }
}

// ---------------------------------------------------------------------------
// K3: cat[e,:] = [ (sum_{n in col e} y[n,:]) - s[e,:] | feature[e,:] ] (bf16).
// One edge per wave, 8192 blocks; s/feature loads hoisted above the gather.
// ---------------------------------------------------------------------------
__global__ __launch_bounds__(256) void pass_b(
    const float* __restrict__ y, const u16* __restrict__ s_bf,
    const float* __restrict__ feature, const int* __restrict__ col_cnt,
    const int* __restrict__ col_nodes, u16* __restrict__ cat)
{
  const int lane = threadIdx.x & 63;
  const int e = blockIdx.x * 4 + (threadIdx.x >> 6);
  const int d0 = lane * 2;
  const int cnt = min(col_cnt[e], COL_CAP);
  const int cnl = col_nodes[(size_t)e * COL_CAP + min(lane, COL_CAP - 1)];
  // issue the independent loads before the gather loop
  const uint32_t sp = *(const uint32_t*)&s_bf[(size_t)e * 128 + d0];
  float2 fv = {0.f, 0.f};
  if (lane < 16) fv = *(const float2*)&feature[e * 32 + lane * 2];
  float a0 = 0.f, a1 = 0.f;
#pragma unroll 4
  for (int j = 0; j < cnt; ++j) {
    const int nn = __shfl(cnl, j);
    const float2 yv = *(const float2*)&y[nn * 128 + d0];
    a0 += yv.x; a1 += yv.y;
  }
  a0 -= bf2f((u16)(sp & 0xffffu));
  a1 -= bf2f((u16)(sp >> 16));
  const uint32_t packed = (uint32_t)f2bf(a0) | ((uint32_t)f2bf(a1) << 16);
  *(uint32_t*)&cat[(size_t)e * 160 + d0] = packed;
  if (lane < 16) {
    const uint32_t pf = (uint32_t)f2bf(fv.x) | ((uint32_t)f2bf(fv.y) << 16);
    *(uint32_t*)&cat[(size_t)e * 160 + 128 + lane * 2] = pf;
  }
}

// ---------------------------------------------------------------------------
// K4: MLP_a: out = ls(ls(cat @ W1a^T + b1a) @ W2a^T), K1=160, f32 out.
// 512 blocks x 64 rows, bf16 weights from wb.
// ---------------------------------------------------------------------------
__global__ __launch_bounds__(256) void mlp_a_kernel(
    const u16* __restrict__ cat, const u16* __restrict__ W1b,
    const float* __restrict__ b1, const u16* __restrict__ W2b,
    float* __restrict__ out)
{
  const int tid = threadIdx.x;
  const int wave = tid >> 6;
  const int lane = tid & 63;
  const int l16 = lane & 15;
  const int quad = lane >> 4;
  const int row0 = blockIdx.x * 64;

  __shared__ u16 h_lds[64][136];

  const f32x4 vzero = {0.f, 0.f, 0.f, 0.f};
  f32x4 acc[8];
  for (int ct = 0; ct < 8; ++ct) acc[ct] = vzero;

  for (int kc = 0; kc < 5; ++kc) {
    const int k0 = kc * 32 + quad * 8;
    BF8 a;
    a.q = *(const uint4*)(cat + (size_t)(row0 + wave * 16 + l16) * 160 + k0);
    for (int ct = 0; ct < 8; ++ct) {
      BF8 b;
      b.q = *(const uint4*)(W1b + (size_t)(ct * 16 + l16) * 160 + k0);
      acc[ct] = __builtin_amdgcn_mfma_f32_16x16x32_bf16(a.v, b.v, acc[ct], 0, 0, 0);
    }
  }

  for (int ct = 0; ct < 8; ++ct) {
    const int col = ct * 16 + l16;
    const float bias = b1[col];
    const int r = wave * 16 + quad * 4;
    for (int i = 0; i < 4; ++i)
      h_lds[r + i][col] = f2bf(logsig(acc[ct][i] + bias));
  }
  __syncthreads();

  f32x4 acc2[8];
  for (int ct = 0; ct < 8; ++ct) acc2[ct] = vzero;

  for (int kc = 0; kc < 4; ++kc) {
    const int k0 = kc * 32 + quad * 8;
    BF8 a;
    a.q = *(const uint4*)&h_lds[wave * 16 + l16][k0];
    for (int ct = 0; ct < 8; ++ct) {
      BF8 b;
      b.q = *(const uint4*)(W2b + (size_t)(ct * 16 + l16) * 128 + k0);
      acc2[ct] = __builtin_amdgcn_mfma_f32_16x16x32_bf16(a.v, b.v, acc2[ct], 0, 0, 0);
    }
  }

  for (int ct = 0; ct < 8; ++ct) {
    const int col = ct * 16 + l16;
    const int r = row0 + wave * 16 + quad * 4;
    for (int i = 0; i < 4; ++i)
      out[(size_t)(r + i) * 128 + col] = logsig(acc2[ct][i]);
  }
}

// ---------------------------------------------------------------------------
// kernel_launch — 5 dispatches; only scan_gather's compaction changed vs R7.
// ---------------------------------------------------------------------------
extern "C" void kernel_launch(void* const* d_in, const int* in_sizes, int n_in,
                              void* d_out, int out_size, void* d_ws, size_t ws_size,
                              hipStream_t stream)
{
  const float* state   = (const float*)d_in[0];
  const float* feature = (const float*)d_in[1];
  const float* mask    = (const float*)d_in[2];
  // d_in[3] = mask_transpose — intentionally unused (== mask.T)
  const float* W1m = (const float*)d_in[4];
  const float* b1m = (const float*)d_in[5];
  const float* W2m = (const float*)d_in[6];
  const float* W1a = (const float*)d_in[7];
  const float* b1a = (const float*)d_in[8];
  const float* W2a = (const float*)d_in[9];
  float* out = (float*)d_out;

  char* ws = (char*)d_ws;
  u16*  s_bf      = (u16*)(ws);                 //  8,388,608 B  [E,128] bf16
  u16*  cat       = (u16*)(ws + 8388608);       // 10,485,760 B  [E,160] bf16
  float* y        = (float*)(ws + 18874368);    //  1,048,576 B  [N,128] f32
  int*  col_cnt   = (int*)(ws + 19922944);      //    131,072 B
  int*  col_nodes = (int*)(ws + 20054016);      //  6,291,456 B
  u16*  wb        = (u16*)(ws + 26345472);      //    139,264 B  bf16 weights

  conv_weights<<<272, 256, 0, stream>>>(W1m, W2m, W1a, W2a, wb, col_cnt);
  mlp_m<<<512, 256, 0, stream>>>(state, wb, b1m, wb + 16384, s_bf);
  scan_gather<<<N_NODES, 256, 0, stream>>>(mask, s_bf, col_cnt, col_nodes, y);
  pass_b<<<N_EDGES / 4, 256, 0, stream>>>(y, s_bf, feature, col_cnt, col_nodes, cat);
  mlp_a_kernel<<<512, 256, 0, stream>>>(cat, wb + 32768, b1a, wb + 53248, out);
}

// Round 9
// 535.387 us; speedup vs baseline: 1.0150x; 1.0150x over previous
//
#include <hip/hip_runtime.h>
#include <cstdint>
#include <cstddef>

#define N_NODES 2048
#define N_EDGES 32768
#define ROW_CAP 384   // max row degree ~222 (mean 164, sd 12.8)
#define COL_CAP 48    // max col degree ~26  (mean 10.2, sd 3.2)

typedef unsigned short u16;
typedef __bf16 bf16x8 __attribute__((ext_vector_type(8)));
typedef float f32x4 __attribute__((ext_vector_type(4)));
typedef uint32_t u32x4 __attribute__((ext_vector_type(4)));

union BF8 {
  bf16x8 v;
  u16 s[8];
  uint4 q;
};

__device__ __forceinline__ u16 f2bf(float f) {
  uint32_t u = __float_as_uint(f);
  uint32_t r = (u + 0x7fffu + ((u >> 16) & 1u)) >> 16;  // RNE
  return (u16)r;
}
__device__ __forceinline__ float bf2f(u16 h) {
  return __uint_as_float(((uint32_t)h) << 16);
}
__device__ __forceinline__ float logsig(float x) {
  return fminf(x, 0.0f) - __logf(1.0f + __expf(-fabsf(x)));
}

// Load 8 consecutive f32 and pack to a bf16x8 MFMA fragment (activations).
__device__ __forceinline__ BF8 load_f32x8_bf(const float* __restrict__ p) {
  const float4 g0 = ((const float4*)p)[0];
  const float4 g1 = ((const float4*)p)[1];
  BF8 b;
  b.s[0] = f2bf(g0.x); b.s[1] = f2bf(g0.y);
  b.s[2] = f2bf(g0.z); b.s[3] = f2bf(g0.w);
  b.s[4] = f2bf(g1.x); b.s[5] = f2bf(g1.y);
  b.s[6] = f2bf(g1.z); b.s[7] = f2bf(g1.w);
  return b;
}

// ---------------------------------------------------------------------------
// K0: weights fp32->bf16 + zero col_cnt. (NEVER inline-convert weights in the
// MFMA hot loop -- measured R5->R7 = -57 us.)
// wb layout (elements): [0,16384)=W1m, [16384,32768)=W2m,
//                       [32768,53248)=W1a(128x160), [53248,69632)=W2a
// ---------------------------------------------------------------------------
__global__ __launch_bounds__(256) void conv_weights(
    const float* __restrict__ W1m, const float* __restrict__ W2m,
    const float* __restrict__ W1a, const float* __restrict__ W2a,
    u16* __restrict__ wb, int* __restrict__ col_cnt)
{
  const int i = blockIdx.x * 256 + threadIdx.x;
  if (i < N_EDGES) col_cnt[i] = 0;
  if (i < 16384)      wb[i] = f2bf(W1m[i]);
  else if (i < 32768) wb[i] = f2bf(W2m[i - 16384]);
  else if (i < 53248) wb[i] = f2bf(W1a[i - 32768]);
  else if (i < 69632) wb[i] = f2bf(W2a[i - 53248]);
}

// ---------------------------------------------------------------------------
// K1: MLP_m  s = ls(ls(state@W1m^T+b1m)@W2m^T) -> bf16.
// 512 blocks x 64 rows: 2 blocks/CU (R7's measured win).
// ---------------------------------------------------------------------------
__global__ __launch_bounds__(256) void mlp_m(
    const float* __restrict__ state, const u16* __restrict__ W1b,
    const float* __restrict__ b1, const u16* __restrict__ W2b,
    u16* __restrict__ s_out)
{
  const int tid = threadIdx.x;
  const int wave = tid >> 6;
  const int lane = tid & 63;
  const int l16 = lane & 15;
  const int quad = lane >> 4;
  const int row0 = blockIdx.x * 64;

  __shared__ u16 h_lds[64][136];

  const f32x4 vzero = {0.f, 0.f, 0.f, 0.f};
  f32x4 acc[8];
  for (int ct = 0; ct < 8; ++ct) acc[ct] = vzero;

  for (int kc = 0; kc < 4; ++kc) {
    const int k0 = kc * 32 + quad * 8;
    const BF8 a = load_f32x8_bf(state + (size_t)(row0 + wave * 16 + l16) * 128 + k0);
    for (int ct = 0; ct < 8; ++ct) {
      BF8 b;
      b.q = *(const uint4*)(W1b + (size_t)(ct * 16 + l16) * 128 + k0);
      acc[ct] = __builtin_amdgcn_mfma_f32_16x16x32_bf16(a.v, b.v, acc[ct], 0, 0, 0);
    }
  }

  for (int ct = 0; ct < 8; ++ct) {
    const int col = ct * 16 + l16;
    const float bias = b1[col];
    const int r = wave * 16 + quad * 4;
    for (int i = 0; i < 4; ++i)
      h_lds[r + i][col] = f2bf(logsig(acc[ct][i] + bias));
  }
  __syncthreads();

  f32x4 acc2[8];
  for (int ct = 0; ct < 8; ++ct) acc2[ct] = vzero;

  for (int kc = 0; kc < 4; ++kc) {
    const int k0 = kc * 32 + quad * 8;
    BF8 a;
    a.q = *(const uint4*)&h_lds[wave * 16 + l16][k0];
    for (int ct = 0; ct < 8; ++ct) {
      BF8 b;
      b.q = *(const uint4*)(W2b + (size_t)(ct * 16 + l16) * 128 + k0);
      acc2[ct] = __builtin_amdgcn_mfma_f32_16x16x32_bf16(a.v, b.v, acc2[ct], 0, 0, 0);
    }
  }

  for (int ct = 0; ct < 8; ++ct) {
    const int col = ct * 16 + l16;
    const int r = row0 + wave * 16 + quad * 4;
    for (int i = 0; i < 4; ++i)
      s_out[(size_t)(r + i) * 128 + col] = f2bf(logsig(acc2[ct][i]));
  }
}

// ---------------------------------------------------------------------------
// K2: fused scan + row-gather. REVERTED to R7's ballot compaction (measured
// best 537.2; R8's per-lane atomic variant was +6.2). Scan is pinned near
// the ~43-48 us HBM floor for the 268 MB mask stream (R5 & R8 nulls).
// ---------------------------------------------------------------------------
__global__ __launch_bounds__(256) void scan_gather(
    const float* __restrict__ mask, const u16* __restrict__ s_bf,
    int* __restrict__ col_cnt, int* __restrict__ col_nodes,
    float* __restrict__ y)
{
  const int n = blockIdx.x;
  const int tid = threadIdx.x;
  const int lane = tid & 63;

  __shared__ int cnt;
  __shared__ int list[ROW_CAP];
  __shared__ float part[3][128];

  if (tid == 0) cnt = 0;
  __syncthreads();

  const u32x4* row = (const u32x4*)(mask + (size_t)n * N_EDGES);
  u32x4 v0 = __builtin_nontemporal_load(&row[tid]);
  u32x4 v1 = __builtin_nontemporal_load(&row[tid + 256]);
#pragma unroll 1
  for (int t = 0; t < 16; ++t) {
    const int i = tid + t * 512;
    u32x4 n0 = {0u, 0u, 0u, 0u}, n1 = {0u, 0u, 0u, 0u};
    if (t < 15) {  // wave-uniform
      n0 = __builtin_nontemporal_load(&row[i + 512]);
      n1 = __builtin_nontemporal_load(&row[i + 768]);
    }
#pragma unroll
    for (int h = 0; h < 2; ++h) {
      const u32x4 v = h ? v1 : v0;
      const int ib = i + h * 256;
      const uint32_t any = v[0] | v[1] | v[2] | v[3];
      const unsigned long long many = __ballot(any != 0u);
      if (many) {
#pragma unroll
        for (int k = 0; k < 4; ++k) {
          const bool p = (v[k] != 0u);
          const unsigned long long m = __ballot(p);
          if (m) {
            int base = 0;
            if (lane == 0) base = atomicAdd(&cnt, __popcll(m));
            base = __shfl(base, 0);
            if (p) {
              const int off = __popcll(m & ((1ull << lane) - 1ull));
              if (base + off < ROW_CAP) list[base + off] = ib * 4 + k;
            }
          }
        }
      }
    }
    v0 = n0; v1 = n1;
  }
  __syncthreads();

  const int c = min(cnt, ROW_CAP);

  // col scatter (feeds pass_b)
  for (int i = tid; i < c; i += 256) {
    const int e = list[i];
    const int slot = atomicAdd(&col_cnt[e], 1);
    if (slot < COL_CAP) col_nodes[(size_t)e * COL_CAP + slot] = n;
  }

  // row gather: 4 waves, each covers all 128 dims (2 dims/lane, u32 loads)
  const int wv = tid >> 6;
  const int d0 = lane * 2;
  float a0 = 0.f, a1 = 0.f;
#pragma unroll 4
  for (int i = wv; i < c; i += 4) {
    const uint32_t sp = *(const uint32_t*)&s_bf[(size_t)list[i] * 128 + d0];
    a0 += bf2f((u16)(sp & 0xffffu));
    a1 += bf2f((u16)(sp >> 16));
  }
  if (wv > 0) { part[wv - 1][d0] = a0; part[wv - 1][d0 + 1] = a1; }
  __syncthreads();
  if (wv == 0) {
    a0 += part[0][d0] + part[1][d0] + part[2][d0];
    a1 += part[0][d0 + 1] + part[1][d0 + 1] + part[2][d0 + 1];
    float2 r; r.x = a0; r.y = a1;
    *(float2*)&y[n * 128 + d0] = r;
  }
}

// ---------------------------------------------------------------------------
// K3: cat[e,:] = [ (sum_{n in col e} y[n,:]) - s[e,:] | feature[e,:] ] (bf16).
// RESTRUCTURED: 2 edges per wave (half-wave per edge, float4 per lane:
// 32 lanes x 4 dims = 128). Same bytes as before, half the waves (4096
// blocks) and half the load instructions; two independent gather chains in
// flight per wave. pass_b solves to ~35-45 us from R4/R7 delta-algebra --
// issue/latency-bound, ~4x above its traffic floor.
// ---------------------------------------------------------------------------
__global__ __launch_bounds__(256) void pass_b(
    const float* __restrict__ y, const u16* __restrict__ s_bf,
    const float* __restrict__ feature, const int* __restrict__ col_cnt,
    const int* __restrict__ col_nodes, u16* __restrict__ cat)
{
  const int lane = threadIdx.x & 63;
  const int half = lane >> 5;          // which edge of the pair
  const int hl = lane & 31;            // lane within half
  const int e = blockIdx.x * 8 + (threadIdx.x >> 6) * 2 + half;
  const int d0 = hl * 4;               // 4 dims per lane

  const int cntv = min(col_cnt[e], COL_CAP);
  // preload first 32 col entries, one per lane of this half
  const int cnl = col_nodes[(size_t)e * COL_CAP + min(hl, COL_CAP - 1)];
  // independent loads issued before the gather loop
  const uint2 sp = *(const uint2*)&s_bf[(size_t)e * 128 + d0];   // 4 bf16
  float2 fv = {0.f, 0.f};
  if (hl < 16) fv = *(const float2*)&feature[e * 32 + hl * 2];

  // wave-uniform loop bound = max over both halves
  const int cA = __shfl(cntv, 0);
  const int cB = __shfl(cntv, 32);
  const int cmax = max(cA, cB);

  float a0 = 0.f, a1 = 0.f, a2 = 0.f, a3 = 0.f;
#pragma unroll 4
  for (int j = 0; j < cmax; ++j) {
    if (j < cntv) {
      const int nn = (j < 32) ? __shfl(cnl, (lane & 32) + j)
                              : col_nodes[(size_t)e * COL_CAP + j];  // never hit (max deg ~26)
      const float4 yv = *(const float4*)&y[nn * 128 + d0];
      a0 += yv.x; a1 += yv.y; a2 += yv.z; a3 += yv.w;
    }
  }
  a0 -= bf2f((u16)(sp.x & 0xffffu));
  a1 -= bf2f((u16)(sp.x >> 16));
  a2 -= bf2f((u16)(sp.y & 0xffffu));
  a3 -= bf2f((u16)(sp.y >> 16));
  uint2 packed;
  packed.x = (uint32_t)f2bf(a0) | ((uint32_t)f2bf(a1) << 16);
  packed.y = (uint32_t)f2bf(a2) | ((uint32_t)f2bf(a3) << 16);
  *(uint2*)&cat[(size_t)e * 160 + d0] = packed;
  if (hl < 16) {
    const uint32_t pf = (uint32_t)f2bf(fv.x) | ((uint32_t)f2bf(fv.y) << 16);
    *(uint32_t*)&cat[(size_t)e * 160 + 128 + hl * 2] = pf;
  }
}

// ---------------------------------------------------------------------------
// K4: MLP_a: out = ls(ls(cat @ W1a^T + b1a) @ W2a^T), K1=160, f32 out.
// 512 blocks x 64 rows, bf16 weights from wb.
// ---------------------------------------------------------------------------
__global__ __launch_bounds__(256) void mlp_a_kernel(
    const u16* __restrict__ cat, const u16* __restrict__ W1b,
    const float* __restrict__ b1, const u16* __restrict__ W2b,
    float* __restrict__ out)
{
  const int tid = threadIdx.x;
  const int wave = tid >> 6;
  const int lane = tid & 63;
  const int l16 = lane & 15;
  const int quad = lane >> 4;
  const int row0 = blockIdx.x * 64;

  __shared__ u16 h_lds[64][136];

  const f32x4 vzero = {0.f, 0.f, 0.f, 0.f};
  f32x4 acc[8];
  for (int ct = 0; ct < 8; ++ct) acc[ct] = vzero;

  for (int kc = 0; kc < 5; ++kc) {
    const int k0 = kc * 32 + quad * 8;
    BF8 a;
    a.q = *(const uint4*)(cat + (size_t)(row0 + wave * 16 + l16) * 160 + k0);
    for (int ct = 0; ct < 8; ++ct) {
      BF8 b;
      b.q = *(const uint4*)(W1b + (size_t)(ct * 16 + l16) * 160 + k0);
      acc[ct] = __builtin_amdgcn_mfma_f32_16x16x32_bf16(a.v, b.v, acc[ct], 0, 0, 0);
    }
  }

  for (int ct = 0; ct < 8; ++ct) {
    const int col = ct * 16 + l16;
    const float bias = b1[col];
    const int r = wave * 16 + quad * 4;
    for (int i = 0; i < 4; ++i)
      h_lds[r + i][col] = f2bf(logsig(acc[ct][i] + bias));
  }
  __syncthreads();

  f32x4 acc2[8];
  for (int ct = 0; ct < 8; ++ct) acc2[ct] = vzero;

  for (int kc = 0; kc < 4; ++kc) {
    const int k0 = kc * 32 + quad * 8;
    BF8 a;
    a.q = *(const uint4*)&h_lds[wave * 16 + l16][k0];
    for (int ct = 0; ct < 8; ++ct) {
      BF8 b;
      b.q = *(const uint4*)(W2b + (size_t)(ct * 16 + l16) * 128 + k0);
      acc2[ct] = __builtin_amdgcn_mfma_f32_16x16x32_bf16(a.v, b.v, acc2[ct], 0, 0, 0);
    }
  }

  for (int ct = 0; ct < 8; ++ct) {
    const int col = ct * 16 + l16;
    const int r = row0 + wave * 16 + quad * 4;
    for (int i = 0; i < 4; ++i)
      out[(size_t)(r + i) * 128 + col] = logsig(acc2[ct][i]);
  }
}

// ---------------------------------------------------------------------------
// kernel_launch — 5 dispatches; scan reverted to R7, pass_b restructured.
// ---------------------------------------------------------------------------
extern "C" void kernel_launch(void* const* d_in, const int* in_sizes, int n_in,
                              void* d_out, int out_size, void* d_ws, size_t ws_size,
                              hipStream_t stream)
{
  const float* state   = (const float*)d_in[0];
  const float* feature = (const float*)d_in[1];
  const float* mask    = (const float*)d_in[2];
  // d_in[3] = mask_transpose — intentionally unused (== mask.T)
  const float* W1m = (const float*)d_in[4];
  const float* b1m = (const float*)d_in[5];
  const float* W2m = (const float*)d_in[6];
  const float* W1a = (const float*)d_in[7];
  const float* b1a = (const float*)d_in[8];
  const float* W2a = (const float*)d_in[9];
  float* out = (float*)d_out;

  char* ws = (char*)d_ws;
  u16*  s_bf      = (u16*)(ws);                 //  8,388,608 B  [E,128] bf16
  u16*  cat       = (u16*)(ws + 8388608);       // 10,485,760 B  [E,160] bf16
  float* y        = (float*)(ws + 18874368);    //  1,048,576 B  [N,128] f32
  int*  col_cnt   = (int*)(ws + 19922944);      //    131,072 B
  int*  col_nodes = (int*)(ws + 20054016);      //  6,291,456 B
  u16*  wb        = (u16*)(ws + 26345472);      //    139,264 B  bf16 weights

  conv_weights<<<272, 256, 0, stream>>>(W1m, W2m, W1a, W2a, wb, col_cnt);
  mlp_m<<<512, 256, 0, stream>>>(state, wb, b1m, wb + 16384, s_bf);
  scan_gather<<<N_NODES, 256, 0, stream>>>(mask, s_bf, col_cnt, col_nodes, y);
  pass_b<<<N_EDGES / 8, 256, 0, stream>>>(y, s_bf, feature, col_cnt, col_nodes, cat);
  mlp_a_kernel<<<512, 256, 0, stream>>>(cat, wb + 32768, b1a, wb + 53248, out);
}